// Round 1
// baseline (217.077 us; speedup 1.0000x reference)
//
#include <hip/hip_runtime.h>
#include <stdint.h>

// JAX threefry counter mode. 1 = partitionable (modern JAX default, >=0.4.30).
// Flip to 0 (legacy split/counter scheme) if outputs mismatch in noise-dominated entries.
#define THREEFRY_PARTITIONABLE 1

#define DEV_HOST __host__ __device__

namespace {
constexpr int kNS      = 10;
constexpr int kSamples = 4096;    // L*B = 128*32
constexpr int kElems   = 262144;  // kSamples * D(=64)

// workspace layout (float offsets)
constexpr int OFF_SUF   = 0;          // S[j][d][h]: 128*64*32 = 262144
constexpr int OFF_BASE  = 262144;     // base[s][h]: 4096*32   = 131072
constexpr int OFF_U     = 393216;     // u[s][d]:    262144
constexpr int OFF_SCORE = 655360;     // score[s][d]:262144
constexpr int OFF_SNRM  = 917504;     // 10 per-step sum-of-squares accumulators
constexpr int OFF_LOSS  = 917514;     // [0]=step_loss acc, [1]=sum|emb-xt| acc
constexpr int WS_FLOATS = 917516;
}

// ---------------- threefry2x32-20 (matches jax/_src/prng.py) ----------------
DEV_HOST inline void tf2x32(uint32_t k0, uint32_t k1, uint32_t x0, uint32_t x1,
                            uint32_t& o0, uint32_t& o1) {
  const uint32_t k2 = k0 ^ k1 ^ 0x1BD11BDAu;
#define TF_R(r) { x0 += x1; x1 = (x1 << (r)) | (x1 >> (32 - (r))); x1 ^= x0; }
  x0 += k0; x1 += k1;
  TF_R(13) TF_R(15) TF_R(26) TF_R(6)
  x0 += k1; x1 += k2 + 1u;
  TF_R(17) TF_R(29) TF_R(16) TF_R(24)
  x0 += k2; x1 += k0 + 2u;
  TF_R(13) TF_R(15) TF_R(26) TF_R(6)
  x0 += k0; x1 += k1 + 3u;
  TF_R(17) TF_R(29) TF_R(16) TF_R(24)
  x0 += k1; x1 += k2 + 4u;
  TF_R(13) TF_R(15) TF_R(26) TF_R(6)
  x0 += k2; x1 += k0 + 5u;
#undef TF_R
  o0 = x0; o1 = x1;
}

__device__ inline uint32_t rand_bits(uint32_t key0, uint32_t key1, uint32_t idx) {
#if THREEFRY_PARTITIONABLE
  // bits[idx] = y0 ^ y1 of cipher(key, hi=0, lo=idx)   (idx < 2^32)
  uint32_t y0, y1;
  tf2x32(key0, key1, 0u, idx, y0, y1);
  return y0 ^ y1;
#else
  // legacy: counts=iota(N), halves (i, N/2+i) per cipher block
  const uint32_t half = kElems / 2;
  uint32_t y0, y1;
  if (idx < half) { tf2x32(key0, key1, idx, half + idx, y0, y1); return y0; }
  tf2x32(key0, key1, idx - half, idx, y0, y1);
  return y1;
#endif
}

// ------------- XLA ErfInv (f32, Giles poly) + jax.random.normal -------------
__device__ inline float erfinv_xla(float x) {
  float w = -log1pf(-x * x);
  float p;
  if (w < 5.0f) {
    w = w - 2.5f;
    p = 2.81022636e-08f;
    p = fmaf(p, w, 3.43273939e-07f);
    p = fmaf(p, w, -3.5233877e-06f);
    p = fmaf(p, w, -4.39150654e-06f);
    p = fmaf(p, w, 0.00021858087f);
    p = fmaf(p, w, -0.00125372503f);
    p = fmaf(p, w, -0.00417768164f);
    p = fmaf(p, w, 0.246640727f);
    p = fmaf(p, w, 1.50140941f);
  } else {
    w = sqrtf(w) - 3.0f;
    p = -0.000200214257f;
    p = fmaf(p, w, 0.000100950558f);
    p = fmaf(p, w, 0.00134934322f);
    p = fmaf(p, w, -0.00367342844f);
    p = fmaf(p, w, 0.00573950773f);
    p = fmaf(p, w, -0.0076224613f);
    p = fmaf(p, w, 0.00943887047f);
    p = fmaf(p, w, 1.00167406f);
    p = fmaf(p, w, 2.83297682f);
  }
  return p * x;
}

__device__ inline float bits_to_normal(uint32_t bits) {
  // uniform: f = bitcast((bits>>9)|0x3f800000) - 1  in [0,1)
  // u = f*(1 - nextafter(-1,0)) + lo ; span rounds to exactly 2.0f, so mul is exact.
  const float lo = -0.99999994039535522f;  // nextafter(-1,0) in f32
  float f = __uint_as_float((bits >> 9) | 0x3f800000u) - 1.0f;
  float u = fmaxf(lo, f * 2.0f + lo);
  return 1.41421356237309515f * erfinv_xla(u);  // sqrt(2) in f32
}

// ---------------------------------------------------------------------------
// S[j][d][h] = sum_{t>j} W1[(t*64+d)*32 + h]
__global__ __launch_bounds__(256) void k_suffix(const float* __restrict__ W1,
                                                float* __restrict__ S) {
  const int p = blockIdx.x * 256 + threadIdx.x;  // 2048 threads: (d,h)
  if (p >= 2048) return;
  const int d = p >> 5, h = p & 31;
  float acc = 0.0f;
  S[(127 * 64 + d) * 32 + h] = 0.0f;
  for (int j = 126; j >= 0; --j) {
    acc += W1[((j + 1) * 64 + d) * 32 + h];
    S[(j * 64 + d) * 32 + h] = acc;
  }
}

// base[s][h] = b1[h] + sum_d emb[b][j][d] * S[j][d][h]   (s = j*32 + b)
__global__ __launch_bounds__(256) void k_base(const float* __restrict__ emb,
                                              const float* __restrict__ S,
                                              const float* __restrict__ b1,
                                              float* __restrict__ base) {
  const int tid = blockIdx.x * 256 + threadIdx.x;  // 131072: (s,h)
  const int s = tid >> 5, h = tid & 31;
  const int j = s >> 5, b = s & 31;
  const float* e = emb + (b * 128 + j) * 64;
  float acc = b1[h];
  for (int d = 0; d < 64; ++d)
    acc = fmaf(e[d], S[(j * 64 + d) * 32 + h], acc);
  base[s * 32 + h] = acc;
}

// Fused per-step kernel: (phase U) apply update for step k-1, (phase S) score k.
// Block owns 8 samples; score[s] depends only on u[s], so no cross-block dep
// inside one kernel. snorm_acc[k-1] is complete at kernel boundary.
__global__ __launch_bounds__(256) void k_step(
    const float* __restrict__ base, float* __restrict__ u,
    const float* __restrict__ W1, const float* __restrict__ W2,
    const float* __restrict__ b2, float* __restrict__ score,
    float* __restrict__ snorm_acc, float* __restrict__ loss_acc,
    int k, float tval, uint32_t key0, uint32_t key1) {
  __shared__ float u_sh[8][64];
  __shared__ float h_sh[8][32];
  __shared__ float wsum[4];
  const int tid = threadIdx.x;
  const int s0 = blockIdx.x * 8;

  if (k > 0) {
    const float snorm = sqrtf(snorm_acc[k - 1]);
#pragma unroll
    for (int r = 0; r < 2; ++r) {
      const int off = r * 256 + tid;     // 0..511 within block
      const int e = s0 * 64 + off;
      const int s = s0 + (off >> 6);     // wave-uniform (64 lanes = 1 sample)
      const float n = bits_to_normal(rand_bits(key0, key1, (uint32_t)e));
      const float dW = n * 0.31622776601683794f;           // sqrtf(0.1f)
      const float dx = score[e] * 0.05f + snorm * dW;      // 0.5*score*DT + snorm*dW
      const float un = u[e] + dx;
      u[e] = un;
      u_sh[off >> 6][off & 63] = un;
      // error[i,e] += mean_d(u^2) for contributing samples (s%128 == s/32)
      if ((s & 127) == (s >> 5)) {
        float sq = un * un;
#pragma unroll
        for (int o = 32; o > 0; o >>= 1) sq += __shfl_down(sq, o);
        if ((tid & 63) == 0) atomicAdd(&loss_acc[0], sq * (1.0f / 64.0f));
      }
    }
  } else {
#pragma unroll
    for (int r = 0; r < 2; ++r) {
      const int off = r * 256 + tid;
      u_sh[off >> 6][off & 63] = u[s0 * 64 + off];  // zeros (memset)
    }
  }
  __syncthreads();

  // phase S part 1: pre-activation + relu, thread = (sample sl, hidden h)
  {
    const int sl = tid >> 5, h = tid & 31;
    const int s = s0 + sl;
    const float* w1r = W1 + ((s & 127) * 64) * 32 + h;
    float pre = base[s * 32 + h] + tval * W1[8192 * 32 + h];
#pragma unroll 16
    for (int d = 0; d < 64; ++d)
      pre = fmaf(u_sh[sl][d], w1r[d * 32], pre);
    h_sh[sl][h] = fmaxf(pre, 0.0f);
  }
  __syncthreads();

  // phase S part 2: score = relu(h) @ W2 + b2, thread = (sl, 2 columns)
  {
    const int sl = tid >> 5, c = tid & 31;
    const int s = s0 + sl;
    float sc0 = b2[c], sc1 = b2[c + 32];
#pragma unroll
    for (int hh = 0; hh < 32; ++hh) {
      const float hv = h_sh[sl][hh];
      sc0 = fmaf(hv, W2[hh * 64 + c], sc0);
      sc1 = fmaf(hv, W2[hh * 64 + c + 32], sc1);
    }
    score[s * 64 + c] = sc0;
    score[s * 64 + c + 32] = sc1;
    float sq = fmaf(sc0, sc0, sc1 * sc1);
#pragma unroll
    for (int o = 32; o > 0; o >>= 1) sq += __shfl_down(sq, o);
    if ((tid & 63) == 0) wsum[tid >> 6] = sq;
  }
  __syncthreads();
  if (tid == 0) atomicAdd(snorm_acc + k, wsum[0] + wsum[1] + wsum[2] + wsum[3]);
}

// final update (step NS-1): u += dx, accumulate error
__global__ __launch_bounds__(256) void k_last(
    float* __restrict__ u, const float* __restrict__ score,
    const float* __restrict__ snorm_acc, float* __restrict__ loss_acc,
    uint32_t key0, uint32_t key1) {
  const int e = blockIdx.x * 256 + threadIdx.x;  // 262144
  const int s = e >> 6;
  const float snorm = sqrtf(snorm_acc[kNS - 1]);
  const float n = bits_to_normal(rand_bits(key0, key1, (uint32_t)e));
  const float dx = score[e] * 0.05f + snorm * (n * 0.31622776601683794f);
  const float un = u[e] + dx;
  u[e] = un;
  if ((s & 127) == (s >> 5)) {
    float sq = un * un;
#pragma unroll
    for (int o = 32; o > 0; o >>= 1) sq += __shfl_down(sq, o);
    if ((threadIdx.x & 63) == 0) atomicAdd(&loss_acc[0], sq * (1.0f / 64.0f));
  }
}

// assemble xt output (the reference's axis-mixing reshape/diag gather) + |emb-xt| sum
__global__ __launch_bounds__(256) void k_final(const float* __restrict__ emb,
                                               const float* __restrict__ u,
                                               float* __restrict__ out,
                                               float* __restrict__ loss_acc) {
  const int g = blockIdx.x * 256 + threadIdx.x;  // g = (b*128+i)*64+d
  const int d = g & 63, bi = g >> 6, i = bi & 127, b = bi >> 7;
  const int m = i * 32 + b;
  const int bp = m >> 7, t = m & 127;
  const int s = i * 32 + bp;
  float v = 0.0f;
  if (i < t) v = emb[(bp * 128 + i) * 64 + d];
  if ((s & 127) == t) v += u[s * 64 + d];
  out[g] = v;
  float ad = fabsf(emb[g] - v);
#pragma unroll
  for (int o = 32; o > 0; o >>= 1) ad += __shfl_down(ad, o);
  __shared__ float wsum[4];
  if ((threadIdx.x & 63) == 0) wsum[threadIdx.x >> 6] = ad;
  __syncthreads();
  if (threadIdx.x == 0) atomicAdd(&loss_acc[1], wsum[0] + wsum[1] + wsum[2] + wsum[3]);
}

__global__ void k_write(float* __restrict__ out, const float* __restrict__ loss_acc) {
  if (threadIdx.x == 0 && blockIdx.x == 0) {
    out[262144] = loss_acc[0];                        // step_loss = sum(error)
    out[262145] = loss_acc[1] * (1.0f / 262144.0f);   // mean |emb - xt|
  }
}

// ---------------------------------------------------------------------------
static void compute_step_keys(uint32_t keys[kNS][2]) {
  // root = jax.random.key(42) -> (0, 42); keys = jax.random.split(root, 10)
#if THREEFRY_PARTITIONABLE
  for (int i = 0; i < kNS; ++i) {
    uint32_t y0, y1;
    tf2x32(0u, 42u, 0u, (uint32_t)i, y0, y1);  // fold-like split: full block output
    keys[i][0] = y0; keys[i][1] = y1;
  }
#else
  uint32_t a[kNS], b[kNS], outw[2 * kNS];
  for (int i = 0; i < kNS; ++i)
    tf2x32(0u, 42u, (uint32_t)i, (uint32_t)(kNS + i), a[i], b[i]);
  for (int i = 0; i < kNS; ++i) { outw[i] = a[i]; outw[kNS + i] = b[i]; }
  for (int i = 0; i < kNS; ++i) { keys[i][0] = outw[2 * i]; keys[i][1] = outw[2 * i + 1]; }
#endif
}

extern "C" void kernel_launch(void* const* d_in, const int* in_sizes, int n_in,
                              void* d_out, int out_size, void* d_ws, size_t ws_size,
                              hipStream_t stream) {
  (void)in_sizes; (void)n_in; (void)out_size; (void)ws_size;
  const float* emb = (const float*)d_in[0];
  const float* W1  = (const float*)d_in[1];
  const float* b1  = (const float*)d_in[2];
  const float* W2  = (const float*)d_in[3];
  const float* b2  = (const float*)d_in[4];
  float* out = (float*)d_out;
  float* ws  = (float*)d_ws;

  float* S     = ws + OFF_SUF;
  float* base  = ws + OFF_BASE;
  float* u     = ws + OFF_U;
  float* score = ws + OFF_SCORE;
  float* snrm  = ws + OFF_SNRM;
  float* loss  = ws + OFF_LOSS;

  uint32_t keys[kNS][2];
  compute_step_keys(keys);

  // zero u + score + accumulators (ws is poisoned 0xAA before every call)
  hipMemsetAsync(u, 0, (size_t)(WS_FLOATS - OFF_U) * sizeof(float), stream);

  k_suffix<<<8, 256, 0, stream>>>(W1, S);
  k_base<<<512, 256, 0, stream>>>(emb, S, b1, base);

  for (int k = 0; k < kNS; ++k) {
    const float tval = (float)k * 0.1f;  // arange(f32) * f32(0.1)
    const uint32_t pk0 = (k > 0) ? keys[k - 1][0] : 0u;
    const uint32_t pk1 = (k > 0) ? keys[k - 1][1] : 0u;
    k_step<<<512, 256, 0, stream>>>(base, u, W1, W2, b2, score, snrm, loss,
                                    k, tval, pk0, pk1);
  }
  k_last<<<1024, 256, 0, stream>>>(u, score, snrm, loss, keys[kNS - 1][0], keys[kNS - 1][1]);
  k_final<<<1024, 256, 0, stream>>>(emb, u, out, loss);
  k_write<<<1, 64, 0, stream>>>(out, loss);
}